// Round 10
// baseline (120.347 us; speedup 1.0000x reference)
//
#include <hip/hip_runtime.h>
#include <hip/hip_fp16.h>
#include <math.h>

#define H_ 192
#define W_ 192
#define HW_ 36864
#define C_ 64
#define O_ 64
#define B_ 2
#define K_ 9
#define EPS_ 1e-5f

typedef __attribute__((ext_vector_type(8))) _Float16 f16x8;  // 8 fp16 = 4 VGPR
typedef __attribute__((ext_vector_type(2))) _Float16 f16x2;
typedef __attribute__((ext_vector_type(4))) float f32x4;

union U16B { uint4 u; __half2 h[4]; };

__device__ __forceinline__ unsigned int pkh(float lo, float hi) {
  return (unsigned int)__half_as_ushort(__float2half(lo)) |
         ((unsigned int)__half_as_ushort(__float2half(hi)) << 16);
}

__device__ __forceinline__ float fdot2f(unsigned int a, unsigned int b, float c) {
#if __has_builtin(__builtin_amdgcn_fdot2)
  union { unsigned int u; f16x2 h; } ua, ub;
  ua.u = a; ub.u = b;
  return __builtin_amdgcn_fdot2(ua.h, ub.h, c, false);
#else
  const __half2 ha = *(const __half2*)&a, hb = *(const __half2*)&b;
  const float2 fa = __half22float2(ha), fb = __half22float2(hb);
  return fmaf(fa.x, fb.x, fmaf(fa.y, fb.y, c));
#endif
}

// ---------------- K1f: fused depthwise+BN+ReLU -> hR fp16, and x -> xR fp16 ----
// Both outputs in gather-coherent layout [b][y][cg][x][8ch].
// grid (HW/256, B, 2): z = channel-half (32 ch) for occupancy.
__global__ __launch_bounds__(256) void k1f(const float* __restrict__ x,
                                           const float* __restrict__ dw_w,
                                           const float* __restrict__ dw_b,
                                           const float* __restrict__ bn_g,
                                           const float* __restrict__ bn_b,
                                           const float* __restrict__ bn_m,
                                           const float* __restrict__ bn_v,
                                           unsigned short* __restrict__ xR,
                                           unsigned short* __restrict__ hR) {
  __shared__ float wls[32][12];  // 9 dw weights + bn scale + bn shift (+pad)
  const int b = blockIdx.y, hf = blockIdx.z;
  const int tid = threadIdx.x;
  for (int i = tid; i < 32 * 12; i += 256) {
    const int cl = i / 12, j = i - cl * 12;
    const int c = hf * 32 + cl;
    if (j < 9) {
      wls[cl][j] = dw_w[c * 9 + j];
    } else if (j == 9) {
      wls[cl][9] = bn_g[c] * rsqrtf(bn_v[c] + EPS_);
    } else if (j == 10) {
      const float sc = bn_g[c] * rsqrtf(bn_v[c] + EPS_);
      wls[cl][10] = fmaf(dw_b[c] - bn_m[c], sc, bn_b[c]);
    }
  }
  __syncthreads();
  const int p = blockIdx.x * 256 + tid;
  const int y = p / W_, xx = p - y * W_;
  const int r0 = max(y - 1, 0) * W_, r1 = y * W_, r2 = min(y + 1, H_ - 1) * W_;
  const int c0 = max(xx - 1, 0), c1 = xx, c2 = min(xx + 1, W_ - 1);
  const float mt = (y > 0) ? 1.f : 0.f, mb = (y < H_ - 1) ? 1.f : 0.f;
  const float ml = (xx > 0) ? 1.f : 0.f, mr = (xx < W_ - 1) ? 1.f : 0.f;
  const float m[9] = {mt * ml, mt, mt * mr, ml, 1.f, mr, mb * ml, mb, mb * mr};
  const int off[9] = {r0 + c0, r0 + c1, r0 + c2, r1 + c0, r1 + c1,
                      r1 + c2, r2 + c0, r2 + c1, r2 + c2};
  const float* xb = x + ((size_t)b * C_ + hf * 32) * HW_;
  uint4* xdst = (uint4*)xR + (size_t)b * HW_ * 8 + (size_t)(y * 8) * W_ + xx;
  uint4* hdst = (uint4*)hR + (size_t)b * HW_ * 8 + (size_t)(y * 8) * W_ + xx;
#pragma unroll
  for (int cc = 0; cc < 4; ++cc) {
    unsigned int hx[4], xv[4];
#pragma unroll
    for (int pr = 0; pr < 4; ++pr) {
      float hv[2], xvv[2];
#pragma unroll
      for (int e = 0; e < 2; ++e) {
        const int cl = cc * 8 + pr * 2 + e;
        const float* pl = xb + (size_t)cl * HW_;
        float s = 0.f;
#pragma unroll
        for (int j = 0; j < 9; ++j)
          s = fmaf(wls[cl][j] * m[j], pl[off[j]], s);
        hv[e] = fmaxf(fmaf(s, wls[cl][9], wls[cl][10]), 0.f);
        xvv[e] = pl[off[4]];
      }
      hx[pr] = pkh(hv[0], hv[1]);
      xv[pr] = pkh(xvv[0], xvv[1]);
    }
    const size_t slot = (size_t)(hf * 4 + cc) * W_;
    xdst[slot] = make_uint4(xv[0], xv[1], xv[2], xv[3]);
    hdst[slot] = make_uint4(hx[0], hx[1], hx[2], hx[3]);
  }
}

// ---------------- K2: pointwise 64->27 (fp16 dot2, fp32 acc), om4 epilogue ----
// om4[b][k][px] = {dy + (ky-1), dx + (kx-1), sigmoid(mask), 0}
__global__ __launch_bounds__(256) void k2_pw(const unsigned short* __restrict__ hR,
                                             const float* __restrict__ pw_w,
                                             const float* __restrict__ pw_b,
                                             float4* __restrict__ om4) {
  __shared__ unsigned int wl2[32 * 28];  // half2 per (c-pair, j), j padded to 28
  const int b = blockIdx.y;
  const int tid = threadIdx.x;
  for (int i = tid; i < 32 * 28; i += 256) {
    const int c2 = i / 28, j = i - c2 * 28;
    wl2[i] = (j < 27) ? pkh(pw_w[j * C_ + 2 * c2], pw_w[j * C_ + 2 * c2 + 1]) : 0u;
  }
  __syncthreads();
  const int p = blockIdx.x * 256 + tid;
  const int y = p / W_, xx = p - y * W_;
  const uint4* hr = (const uint4*)hR + (size_t)b * HW_ * 8 + (size_t)(y * 8) * W_ + xx;
  float s[28];
#pragma unroll
  for (int j = 0; j < 28; ++j) s[j] = 0.f;
#pragma unroll
  for (int cg = 0; cg < 8; ++cg) {
    const uint4 hv = hr[(size_t)cg * W_];
    const unsigned int hu[4] = {hv.x, hv.y, hv.z, hv.w};
#pragma unroll
    for (int q = 0; q < 4; ++q) {
      const int c2 = (cg << 2) + q;
      const uint4* w4 = (const uint4*)&wl2[c2 * 28];
#pragma unroll
      for (int t7 = 0; t7 < 7; ++t7) {
        const uint4 ww = w4[t7];
        s[t7 * 4 + 0] = fdot2f(hu[q], ww.x, s[t7 * 4 + 0]);
        s[t7 * 4 + 1] = fdot2f(hu[q], ww.y, s[t7 * 4 + 1]);
        s[t7 * 4 + 2] = fdot2f(hu[q], ww.z, s[t7 * 4 + 2]);
        s[t7 * 4 + 3] = fdot2f(hu[q], ww.w, s[t7 * 4 + 3]);
      }
    }
  }
  float4* op = om4 + (size_t)b * 9 * HW_;
#pragma unroll
  for (int k = 0; k < 9; ++k) {
    const float ry = (float)(k / 3 - 1), rx = (float)(k % 3 - 1);
    float4 v;
    v.x = s[2 * k] + pw_b[2 * k] + ry;
    v.y = s[2 * k + 1] + pw_b[2 * k + 1] + rx;
    v.z = 1.f / (1.f + __expf(-(s[18 + k] + pw_b[18 + k])));
    v.w = 0.f;
    op[(size_t)k * HW_ + p] = v;
  }
}

// ---------------- K0: dcn_w (O,C,3,3) fp32 -> wT2[k][o][c] fp16 ----------------
__global__ __launch_bounds__(256) void k0_wt(const float* __restrict__ dcn_w,
                                             unsigned short* __restrict__ wT2) {
  const int i = blockIdx.x * 256 + threadIdx.x;  // (o*C + c)*9 + k
  const int o = i / (C_ * 9);
  const int rem = i - o * (C_ * 9);
  const int c = rem / 9;
  const int kk = rem - c * 9;
  wT2[((size_t)(kk * O_) + o) * C_ + c] = __half_as_ushort(__float2half(dcn_w[i]));
}

// ---------------- K3: fused deformable gather (fp16 pk) + MFMA f16 contraction --
// 64-px tile, 64 o, 256 threads (4 waves). Wave cq: channel-groups {cq,cq+4},
// o-strip cq*16. Interp fully packed fp16 (__hfma2). Output pre16 (fp16).
__global__ __launch_bounds__(256, 4) void k3_dcn(const unsigned short* __restrict__ xR,
                                                 const float4* __restrict__ om4,
                                                 const unsigned short* __restrict__ wT2,
                                                 unsigned short* __restrict__ pre16,
                                                 float* __restrict__ pstats2) {
  __shared__ __align__(16) unsigned short smem[8192];  // 16 KB, dual-use
  unsigned short* wlds = smem;         // [o][c] fp16 swz, 8 KB
  unsigned short* vlds = smem + 4096;  // [px][c] fp16 swz, 8 KB

  const int tid = threadIdx.x;
  // bijective XCD swizzle: 1152 blocks = 8 XCD x 144 contiguous tiles
  const int t = (blockIdx.x & 7) * 144 + (blockIdx.x >> 3);
  const int b = t / 576;
  const int p0 = (t - b * 576) * 64;
  const uint4* xr = (const uint4*)xR + (size_t)b * HW_ * 8;
  const float4* omb = om4 + (size_t)b * 9 * HW_;

  const int pxi = tid & 63;   // gather pixel
  const int cq = tid >> 6;    // wave id == channel-group slot == o-strip/16
  const int lr = pxi & 15;    // lane&15
  const int lg = pxi >> 4;    // lane>>4 (k-group)
  const int oo0 = cq * 16;

  const int p = p0 + pxi;
  const int y = p / W_;
  const int xx = p - y * W_;

  f32x4 acc[4];
#pragma unroll
  for (int j = 0; j < 4; ++j) acc[j] = (f32x4){0.f, 0.f, 0.f, 0.f};

  for (int k = 0; k < K_; ++k) {
    // --- issue w-stage loads early (L1/L2-resident, 2 x 16B per thread)
    const uint4* wsrc = (const uint4*)(wT2 + (k << 12));
    const uint4 wv0 = wsrc[tid];
    const uint4 wv1 = wsrc[tid + 256];
    // --- packed coords: one float4 per tap (ky/kx + bias + sigmoid pre-folded)
    const float4 od = omb[(size_t)k * HW_ + p];
    const float py = (float)y + od.x;
    const float pxf = (float)xx + od.y;
    const float mk = od.z;
    const float y0f = floorf(py), x0f = floorf(pxf);
    const float wy1 = py - y0f, wx1 = pxf - x0f;
    const float wy0 = 1.f - wy1, wx0 = 1.f - wx1;
    const int y0 = (int)y0f, x0i = (int)x0f;
    const int y1 = y0 + 1, x1i = x0i + 1;
    const bool vy0 = (y0 >= 0) & (y0 < H_);
    const bool vy1 = (y1 >= 0) & (y1 < H_);
    const bool vx0 = (x0i >= 0) & (x0i < W_);
    const bool vx1 = (x1i >= 0) & (x1i < W_);
    const int yc0 = min(max(y0, 0), H_ - 1), yc1 = min(max(y1, 0), H_ - 1);
    const int xc0 = min(max(x0i, 0), W_ - 1), xc1 = min(max(x1i, 0), W_ - 1);
    const float g0 = (vy0 & vx0) ? wy0 * wx0 * mk : 0.f;
    const float g1 = (vy0 & vx1) ? wy0 * wx1 * mk : 0.f;
    const float g2 = (vy1 & vx0) ? wy1 * wx0 * mk : 0.f;
    const float g3 = (vy1 & vx1) ? wy1 * wx1 * mk : 0.f;

    // --- x-coherent gather: 8 x 16B loads (4 corners x 2 channel-groups)
    const int ry0 = yc0 * (8 * W_), ry1 = yc1 * (8 * W_);
    const int ca = cq * W_, cb = (cq + 4) * W_;
    U16B a0, a1, a2, a3, b0v, b1v, b2v, b3v;
    a0.u = xr[ry0 + ca + xc0];  b0v.u = xr[ry0 + cb + xc0];
    a1.u = xr[ry0 + ca + xc1];  b1v.u = xr[ry0 + cb + xc1];
    a2.u = xr[ry1 + ca + xc0];  b2v.u = xr[ry1 + cb + xc0];
    a3.u = xr[ry1 + ca + xc1];  b3v.u = xr[ry1 + cb + xc1];

    // --- packed fp16 interpolation: 32 x v_pk_fma_f16, no unpack/repack
    const __half2 g0h = __float2half2_rn(g0);
    const __half2 g1h = __float2half2_rn(g1);
    const __half2 g2h = __float2half2_rn(g2);
    const __half2 g3h = __float2half2_rn(g3);
    U16B va, vb;
    va.u = make_uint4(0, 0, 0, 0);
    vb.u = make_uint4(0, 0, 0, 0);
#pragma unroll
    for (int i = 0; i < 4; ++i) {
      va.h[i] = __hfma2(a0.h[i], g0h, va.h[i]);
      vb.h[i] = __hfma2(b0v.h[i], g0h, vb.h[i]);
      va.h[i] = __hfma2(a1.h[i], g1h, va.h[i]);
      vb.h[i] = __hfma2(b1v.h[i], g1h, vb.h[i]);
      va.h[i] = __hfma2(a2.h[i], g2h, va.h[i]);
      vb.h[i] = __hfma2(b2v.h[i], g2h, vb.h[i]);
      va.h[i] = __hfma2(a3.h[i], g3h, va.h[i]);
      vb.h[i] = __hfma2(b3v.h[i], g3h, vb.h[i]);
    }

    __syncthreads();  // (A) all waves done MFMA-reading previous tap's LDS
    // --- stage w tap (swizzled 16B blocks): block index i -> row i>>3, blk i&7
    {
      const int r0 = tid >> 3, b0i = tid & 7;
      ((uint4*)wlds)[(r0 << 3) + (b0i ^ (r0 & 7))] = wv0;
      const int r1 = (tid + 256) >> 3;
      ((uint4*)wlds)[(r1 << 3) + (b0i ^ (r1 & 7))] = wv1;
    }
    // --- write vlds rows (already packed fp16; swizzled)
    {
      const int rsw = pxi & 7;
      ((uint4*)vlds)[(pxi << 3) + (cq ^ rsw)] = va.u;
      ((uint4*)vlds)[(pxi << 3) + ((cq + 4) ^ rsw)] = vb.u;
    }
    __syncthreads();  // (B) wlds + vlds ready
    // --- MFMA: D[o-strip 16][px 64] += w[o][c] * val[c][px], K=64 in 2 steps
#pragma unroll
    for (int ks = 0; ks < 2; ++ks) {
      const int kb = (ks << 2) + lg;
      const int ra = oo0 + lr;
      const f16x8 afr = *(const f16x8*)&((const uint4*)wlds)[(ra << 3) + (kb ^ (ra & 7))];
#pragma unroll
      for (int j = 0; j < 4; ++j) {
        const int rb = (j << 4) + lr;
        const f16x8 bfr = *(const f16x8*)&((const uint4*)vlds)[(rb << 3) + (kb ^ (rb & 7))];
        acc[j] = __builtin_amdgcn_mfma_f32_16x16x32_f16(afr, bfr, acc[j], 0, 0, 0);
      }
    }
  }

  // --- per-block IN partial stats (register-only; no atomics; deterministic)
#pragma unroll
  for (int q = 0; q < 4; ++q) {
    float s = acc[0][q] + acc[1][q] + acc[2][q] + acc[3][q];
    float s2 = fmaf(acc[0][q], acc[0][q],
               fmaf(acc[1][q], acc[1][q],
               fmaf(acc[2][q], acc[2][q], acc[3][q] * acc[3][q])));
#pragma unroll
    for (int m = 1; m < 16; m <<= 1) {
      s += __shfl_xor(s, m);
      s2 += __shfl_xor(s2, m);
    }
    if (lr == 0) {
      const int pll = oo0 + (lg << 2) + q;
      ((float2*)pstats2)[(size_t)t * 64 + pll] = make_float2(s, s2);
    }
  }

  // --- epilogue: transpose through (now dead) LDS -> coalesced fp16 stores
  __syncthreads();  // all MFMA reads of smem done
  float* fsm = (float*)smem;  // [64 o][64 px] f32 = 16 KB
#pragma unroll
  for (int j = 0; j < 4; ++j)
#pragma unroll
    for (int q = 0; q < 4; ++q)
      fsm[(oo0 + (lg << 2) + q) * 64 + (j << 4) + lr] = acc[j][q];
  __syncthreads();
  {
    const float4* fsm4 = (const float4*)fsm;
    unsigned short* prebase = pre16 + (size_t)b * O_ * HW_ + p0;
#pragma unroll
    for (int i = 0; i < 4; ++i) {
      const int f = tid + (i << 8);
      const int o = f >> 4;
      const int px4 = (f & 15) << 2;
      const float4 v = fsm4[f];
      uint2 pk;
      pk.x = pkh(v.x, v.y);
      pk.y = pkh(v.z, v.w);
      *(uint2*)&prebase[(size_t)o * HW_ + px4] = pk;
    }
  }
}

// ---------------- K4: finalize stats from per-tile partials ----------------
__global__ __launch_bounds__(256) void k4_fin(const float* __restrict__ pstats2,
                                              float* __restrict__ stats) {
  const int pl = blockIdx.x;  // 0..127 = b*O + o
  const int b = pl >> 6, o = pl & 63;
  const float2* src = (const float2*)pstats2 + (size_t)b * 576 * 64 + o;
  float s = 0.f, s2 = 0.f;
  for (int tt = threadIdx.x; tt < 576; tt += 256) {
    const float2 v = src[(size_t)tt * 64];
    s += v.x;
    s2 += v.y;
  }
#pragma unroll
  for (int m = 1; m < 64; m <<= 1) {
    s += __shfl_xor(s, m);
    s2 += __shfl_xor(s2, m);
  }
  __shared__ float ls[4], ls2[4];
  const int wid = threadIdx.x >> 6;
  if ((threadIdx.x & 63) == 0) { ls[wid] = s; ls2[wid] = s2; }
  __syncthreads();
  if (threadIdx.x == 0) {
    const float ts = ls[0] + ls[1] + ls[2] + ls[3];
    const float ts2 = ls2[0] + ls2[1] + ls2[2] + ls2[3];
    const float inv = 1.f / (float)HW_;
    const float mu = ts * inv;
    const float var = fmaxf(fmaf(-mu, mu, ts2 * inv), 0.f);
    stats[pl * 2] = mu;
    stats[pl * 2 + 1] = rsqrtf(var + EPS_);
  }
}

// ---------------- K5: apply instance norm + ReLU (fp16 in, fp32 out) ----------
__global__ __launch_bounds__(256) void k5_norm(const unsigned short* __restrict__ pre16,
                                               const float* __restrict__ stats,
                                               float* __restrict__ out) {
  const int i4 = blockIdx.x * 256 + threadIdx.x;  // 4-px unit
  const int plane = i4 / 9216;
  const float mu = stats[plane * 2];
  const float rs = stats[plane * 2 + 1];
  const uint2 pk = ((const uint2*)pre16)[i4];
  const __half2 h0 = *(const __half2*)&pk.x;
  const __half2 h1 = *(const __half2*)&pk.y;
  const float2 f0 = __half22float2(h0);
  const float2 f1 = __half22float2(h1);
  float4 v;
  v.x = fmaxf((f0.x - mu) * rs, 0.f);
  v.y = fmaxf((f0.y - mu) * rs, 0.f);
  v.z = fmaxf((f1.x - mu) * rs, 0.f);
  v.w = fmaxf((f1.y - mu) * rs, 0.f);
  ((float4*)out)[i4] = v;
}

extern "C" void kernel_launch(void* const* d_in, const int* in_sizes, int n_in,
                              void* d_out, int out_size, void* d_ws, size_t ws_size,
                              hipStream_t stream) {
  const float* x = (const float*)d_in[0];
  const float* dw_w = (const float*)d_in[1];
  const float* dw_b = (const float*)d_in[2];
  const float* bn_g = (const float*)d_in[3];
  const float* bn_b = (const float*)d_in[4];
  const float* bn_m = (const float*)d_in[5];
  const float* bn_v = (const float*)d_in[6];
  const float* pw_w = (const float*)d_in[7];
  const float* pw_b = (const float*)d_in[8];
  const float* dcn_w = (const float*)d_in[9];
  float* out = (float*)d_out;

  // workspace layout
  unsigned short* pre16 = (unsigned short*)d_ws;            // B*O*HW fp16 = 9.4 MB
  unsigned short* hR = pre16 + (size_t)B_ * O_ * HW_;       // B*HW*64 fp16 = 9.4 MB
  float4* om4 = (float4*)(hR + (size_t)B_ * HW_ * C_);      // B*9*HW float4 = 10.6 MB
  unsigned short* wT2 = (unsigned short*)(om4 + (size_t)B_ * 9 * HW_);  // 36864 u16
  float* stats = (float*)(wT2 + (size_t)K_ * O_ * C_);      // 256 floats
  if (ws_size < (size_t)(9437184 + 9437184 + 10616832 + 73728 + 1024)) return;
  // xR (gather-layout fp16, 9.4 MB) + pstats2 (590 KB) live in d_out:
  // both dead before k5 overwrites d_out.
  unsigned short* xR = (unsigned short*)d_out;
  float* pstats2 = (float*)d_out + 2359296;  // after xR

  k0_wt<<<dim3(144), dim3(256), 0, stream>>>(dcn_w, wT2);
  k1f<<<dim3(HW_ / 256, B_, 2), dim3(256), 0, stream>>>(x, dw_w, dw_b, bn_g, bn_b,
                                                        bn_m, bn_v, xR, hR);
  k2_pw<<<dim3(HW_ / 256, B_), dim3(256), 0, stream>>>(hR, pw_w, pw_b, om4);
  k3_dcn<<<dim3(B_ * HW_ / 64), dim3(256), 0, stream>>>(xR, om4, wT2, pre16, pstats2);
  k4_fin<<<dim3(B_ * O_), dim3(256), 0, stream>>>(pstats2, stats);
  k5_norm<<<dim3(B_ * O_ * HW_ / 4 / 256), dim3(256), 0, stream>>>(pre16, stats, out);
}

// Round 11
// 103.181 us; speedup vs baseline: 1.1664x; 1.1664x over previous
//
#include <hip/hip_runtime.h>
#include <hip/hip_fp16.h>
#include <math.h>

#define H_ 192
#define W_ 192
#define HW_ 36864
#define C_ 64
#define O_ 64
#define B_ 2
#define K_ 9
#define EPS_ 1e-5f

typedef __attribute__((ext_vector_type(8))) _Float16 f16x8;  // 8 fp16 = 4 VGPR
typedef __attribute__((ext_vector_type(4))) float f32x4;

union U16B { uint4 u; __half2 h[4]; };

__device__ __forceinline__ unsigned int pkh(float lo, float hi) {
  return (unsigned int)__half_as_ushort(__float2half(lo)) |
         ((unsigned int)__half_as_ushort(__float2half(hi)) << 16);
}

// ---------------- K1: depthwise 3x3 conv + bias + BN + ReLU -> h ----------------
__global__ __launch_bounds__(256) void k1_dw(const float* __restrict__ x,
                                             const float* __restrict__ dw_w,
                                             const float* __restrict__ dw_b,
                                             const float* __restrict__ bn_g,
                                             const float* __restrict__ bn_b,
                                             const float* __restrict__ bn_m,
                                             const float* __restrict__ bn_v,
                                             float* __restrict__ h) {
  const int plane = blockIdx.y;                 // b*C + c
  const int c = plane & (C_ - 1);
  const int p = blockIdx.x * 256 + threadIdx.x;
  const int y = p / W_;
  const int xx = p - y * W_;
  const float* xp = x + (size_t)plane * HW_;
  float w[9];
#pragma unroll
  for (int i = 0; i < 9; ++i) w[i] = dw_w[c * 9 + i];
  float s = 0.f;
#pragma unroll
  for (int dy = 0; dy < 3; ++dy) {
    const int yy = y + dy - 1;
    if (yy < 0 || yy >= H_) continue;
#pragma unroll
    for (int dx = 0; dx < 3; ++dx) {
      const int xc = xx + dx - 1;
      if (xc < 0 || xc >= W_) continue;
      s = fmaf(w[dy * 3 + dx], xp[yy * W_ + xc], s);
    }
  }
  const float scale = bn_g[c] * rsqrtf(bn_v[c] + EPS_);
  const float shift = fmaf(dw_b[c] - bn_m[c], scale, bn_b[c]);
  h[(size_t)plane * HW_ + p] = fmaxf(fmaf(s, scale, shift), 0.f);
}

// ---------------- K1b: x NCHW fp32 -> xR[b][y][cg][x][8ch] fp16 ----------------
__global__ __launch_bounds__(256) void k1b_t(const float* __restrict__ x,
                                             unsigned short* __restrict__ xR) {
  const int b = blockIdx.y;
  const int p = blockIdx.x * 256 + threadIdx.x;
  const int y = p / W_;
  const int xx = p - y * W_;
  const float* xp = x + (size_t)b * C_ * HW_ + p;
  uint4* dst = (uint4*)xR + (size_t)b * HW_ * 8;
#pragma unroll
  for (int cc = 0; cc < 8; ++cc) {
    uint4 u;
    u.x = pkh(xp[(size_t)(cc * 8 + 0) * HW_], xp[(size_t)(cc * 8 + 1) * HW_]);
    u.y = pkh(xp[(size_t)(cc * 8 + 2) * HW_], xp[(size_t)(cc * 8 + 3) * HW_]);
    u.z = pkh(xp[(size_t)(cc * 8 + 4) * HW_], xp[(size_t)(cc * 8 + 5) * HW_]);
    u.w = pkh(xp[(size_t)(cc * 8 + 6) * HW_], xp[(size_t)(cc * 8 + 7) * HW_]);
    dst[(y * 8 + cc) * W_ + xx] = u;
  }
}

// ---------------- K2: pointwise 64->27 per pixel (1 px/thread), om4 epilogue ---
// om4[b][k][px] = {dy + (ky-1), dx + (kx-1), sigmoid(mask), 0}
__global__ __launch_bounds__(256) void k2_pw(const float* __restrict__ h,
                                             const float* __restrict__ pw_w,
                                             const float* __restrict__ pw_b,
                                             float4* __restrict__ om4) {
  __shared__ float wl[C_ * 28];
  const int b = blockIdx.y;
  const int p = blockIdx.x * 256 + threadIdx.x;
  for (int i = threadIdx.x; i < C_ * 28; i += 256) {
    const int c = i / 28, j = i - c * 28;
    wl[i] = (j < 27) ? pw_w[j * C_ + c] : 0.f;
  }
  __syncthreads();
  float s[27];
#pragma unroll
  for (int j = 0; j < 27; ++j) s[j] = 0.f;
  const float* hp = h + (size_t)b * C_ * HW_ + p;
  for (int c = 0; c < C_; ++c) {
    const float hv = hp[(size_t)c * HW_];
    float wv[28];
#pragma unroll
    for (int q = 0; q < 7; ++q)
      *(float4*)&wv[q * 4] = *(const float4*)&wl[c * 28 + q * 4];
#pragma unroll
    for (int j = 0; j < 27; ++j) s[j] = fmaf(hv, wv[j], s[j]);
  }
  float4* op = om4 + (size_t)b * 9 * HW_;
#pragma unroll
  for (int k = 0; k < 9; ++k) {
    const float ry = (float)(k / 3 - 1), rx = (float)(k % 3 - 1);
    float4 v;
    v.x = s[2 * k] + pw_b[2 * k] + ry;
    v.y = s[2 * k + 1] + pw_b[2 * k + 1] + rx;
    v.z = 1.f / (1.f + __expf(-(s[18 + k] + pw_b[18 + k])));
    v.w = 0.f;
    op[(size_t)k * HW_ + p] = v;
  }
}

// ---------------- K0: dcn_w (O,C,3,3) fp32 -> wT2[k][o][c] fp16 ----------------
__global__ __launch_bounds__(256) void k0_wt(const float* __restrict__ dcn_w,
                                             unsigned short* __restrict__ wT2) {
  const int i = blockIdx.x * 256 + threadIdx.x;  // (o*C + c)*9 + k
  const int o = i / (C_ * 9);
  const int rem = i - o * (C_ * 9);
  const int c = rem / 9;
  const int kk = rem - c * 9;
  wT2[((size_t)(kk * O_) + o) * C_ + c] = __half_as_ushort(__float2half(dcn_w[i]));
}

// ---------------- K3: fused deformable gather (fp16 pk) + MFMA f16 contraction --
// 64-px tile, 64 o, 256 threads (4 waves). Wave cq: channel-groups {cq,cq+4},
// o-strip cq*16. Interp fully packed fp16 (__hfma2). Output pre16 (fp16).
__global__ __launch_bounds__(256, 4) void k3_dcn(const unsigned short* __restrict__ xR,
                                                 const float4* __restrict__ om4,
                                                 const unsigned short* __restrict__ wT2,
                                                 unsigned short* __restrict__ pre16,
                                                 float* __restrict__ pstats2) {
  __shared__ __align__(16) unsigned short smem[8192];  // 16 KB, dual-use
  unsigned short* wlds = smem;         // [o][c] fp16 swz, 8 KB
  unsigned short* vlds = smem + 4096;  // [px][c] fp16 swz, 8 KB

  const int tid = threadIdx.x;
  // bijective XCD swizzle: 1152 blocks = 8 XCD x 144 contiguous tiles
  const int t = (blockIdx.x & 7) * 144 + (blockIdx.x >> 3);
  const int b = t / 576;
  const int p0 = (t - b * 576) * 64;
  const uint4* xr = (const uint4*)xR + (size_t)b * HW_ * 8;
  const float4* omb = om4 + (size_t)b * 9 * HW_;

  const int pxi = tid & 63;   // gather pixel
  const int cq = tid >> 6;    // wave id == channel-group slot == o-strip/16
  const int lr = pxi & 15;    // lane&15
  const int lg = pxi >> 4;    // lane>>4 (k-group)
  const int oo0 = cq * 16;

  const int p = p0 + pxi;
  const int y = p / W_;
  const int xx = p - y * W_;

  f32x4 acc[4];
#pragma unroll
  for (int j = 0; j < 4; ++j) acc[j] = (f32x4){0.f, 0.f, 0.f, 0.f};

  for (int k = 0; k < K_; ++k) {
    // --- issue w-stage loads early (L1/L2-resident, 2 x 16B per thread)
    const uint4* wsrc = (const uint4*)(wT2 + (k << 12));
    const uint4 wv0 = wsrc[tid];
    const uint4 wv1 = wsrc[tid + 256];
    // --- packed coords: one float4 per tap (ky/kx + bias + sigmoid pre-folded)
    const float4 od = omb[(size_t)k * HW_ + p];
    const float py = (float)y + od.x;
    const float pxf = (float)xx + od.y;
    const float mk = od.z;
    const float y0f = floorf(py), x0f = floorf(pxf);
    const float wy1 = py - y0f, wx1 = pxf - x0f;
    const float wy0 = 1.f - wy1, wx0 = 1.f - wx1;
    const int y0 = (int)y0f, x0i = (int)x0f;
    const int y1 = y0 + 1, x1i = x0i + 1;
    const bool vy0 = (y0 >= 0) & (y0 < H_);
    const bool vy1 = (y1 >= 0) & (y1 < H_);
    const bool vx0 = (x0i >= 0) & (x0i < W_);
    const bool vx1 = (x1i >= 0) & (x1i < W_);
    const int yc0 = min(max(y0, 0), H_ - 1), yc1 = min(max(y1, 0), H_ - 1);
    const int xc0 = min(max(x0i, 0), W_ - 1), xc1 = min(max(x1i, 0), W_ - 1);
    const float g0 = (vy0 & vx0) ? wy0 * wx0 * mk : 0.f;
    const float g1 = (vy0 & vx1) ? wy0 * wx1 * mk : 0.f;
    const float g2 = (vy1 & vx0) ? wy1 * wx0 * mk : 0.f;
    const float g3 = (vy1 & vx1) ? wy1 * wx1 * mk : 0.f;

    // --- x-coherent gather: 8 x 16B loads (4 corners x 2 channel-groups)
    const int ry0 = yc0 * (8 * W_), ry1 = yc1 * (8 * W_);
    const int ca = cq * W_, cb = (cq + 4) * W_;
    U16B a0, a1, a2, a3, b0v, b1v, b2v, b3v;
    a0.u = xr[ry0 + ca + xc0];  b0v.u = xr[ry0 + cb + xc0];
    a1.u = xr[ry0 + ca + xc1];  b1v.u = xr[ry0 + cb + xc1];
    a2.u = xr[ry1 + ca + xc0];  b2v.u = xr[ry1 + cb + xc0];
    a3.u = xr[ry1 + ca + xc1];  b3v.u = xr[ry1 + cb + xc1];

    // --- packed fp16 interpolation: 32 x v_pk_fma_f16, no unpack/repack
    const __half2 g0h = __float2half2_rn(g0);
    const __half2 g1h = __float2half2_rn(g1);
    const __half2 g2h = __float2half2_rn(g2);
    const __half2 g3h = __float2half2_rn(g3);
    U16B va, vb;
    va.u = make_uint4(0, 0, 0, 0);
    vb.u = make_uint4(0, 0, 0, 0);
#pragma unroll
    for (int i = 0; i < 4; ++i) {
      va.h[i] = __hfma2(a0.h[i], g0h, va.h[i]);
      vb.h[i] = __hfma2(b0v.h[i], g0h, vb.h[i]);
      va.h[i] = __hfma2(a1.h[i], g1h, va.h[i]);
      vb.h[i] = __hfma2(b1v.h[i], g1h, vb.h[i]);
      va.h[i] = __hfma2(a2.h[i], g2h, va.h[i]);
      vb.h[i] = __hfma2(b2v.h[i], g2h, vb.h[i]);
      va.h[i] = __hfma2(a3.h[i], g3h, va.h[i]);
      vb.h[i] = __hfma2(b3v.h[i], g3h, vb.h[i]);
    }

    __syncthreads();  // (A) all waves done MFMA-reading previous tap's LDS
    // --- stage w tap (swizzled 16B blocks): block index i -> row i>>3, blk i&7
    {
      const int r0 = tid >> 3, b0i = tid & 7;
      ((uint4*)wlds)[(r0 << 3) + (b0i ^ (r0 & 7))] = wv0;
      const int r1 = (tid + 256) >> 3;
      ((uint4*)wlds)[(r1 << 3) + (b0i ^ (r1 & 7))] = wv1;
    }
    // --- write vlds rows (already packed fp16; swizzled)
    {
      const int rsw = pxi & 7;
      ((uint4*)vlds)[(pxi << 3) + (cq ^ rsw)] = va.u;
      ((uint4*)vlds)[(pxi << 3) + ((cq + 4) ^ rsw)] = vb.u;
    }
    __syncthreads();  // (B) wlds + vlds ready
    // --- MFMA: D[o-strip 16][px 64] += w[o][c] * val[c][px], K=64 in 2 steps
#pragma unroll
    for (int ks = 0; ks < 2; ++ks) {
      const int kb = (ks << 2) + lg;
      const int ra = oo0 + lr;
      const f16x8 afr = *(const f16x8*)&((const uint4*)wlds)[(ra << 3) + (kb ^ (ra & 7))];
#pragma unroll
      for (int j = 0; j < 4; ++j) {
        const int rb = (j << 4) + lr;
        const f16x8 bfr = *(const f16x8*)&((const uint4*)vlds)[(rb << 3) + (kb ^ (rb & 7))];
        acc[j] = __builtin_amdgcn_mfma_f32_16x16x32_f16(afr, bfr, acc[j], 0, 0, 0);
      }
    }
  }

  // --- per-block IN partial stats (register-only; no atomics; deterministic)
#pragma unroll
  for (int q = 0; q < 4; ++q) {
    float s = acc[0][q] + acc[1][q] + acc[2][q] + acc[3][q];
    float s2 = fmaf(acc[0][q], acc[0][q],
               fmaf(acc[1][q], acc[1][q],
               fmaf(acc[2][q], acc[2][q], acc[3][q] * acc[3][q])));
#pragma unroll
    for (int m = 1; m < 16; m <<= 1) {
      s += __shfl_xor(s, m);
      s2 += __shfl_xor(s2, m);
    }
    if (lr == 0) {
      const int pll = oo0 + (lg << 2) + q;
      ((float2*)pstats2)[(size_t)t * 64 + pll] = make_float2(s, s2);
    }
  }

  // --- epilogue: transpose through (now dead) LDS -> coalesced fp16 stores
  __syncthreads();  // all MFMA reads of smem done
  float* fsm = (float*)smem;  // [64 o][64 px] f32 = 16 KB
#pragma unroll
  for (int j = 0; j < 4; ++j)
#pragma unroll
    for (int q = 0; q < 4; ++q)
      fsm[(oo0 + (lg << 2) + q) * 64 + (j << 4) + lr] = acc[j][q];
  __syncthreads();
  {
    const float4* fsm4 = (const float4*)fsm;
    unsigned short* prebase = pre16 + (size_t)b * O_ * HW_ + p0;
#pragma unroll
    for (int i = 0; i < 4; ++i) {
      const int f = tid + (i << 8);
      const int o = f >> 4;
      const int px4 = (f & 15) << 2;
      const float4 v = fsm4[f];
      uint2 pk;
      pk.x = pkh(v.x, v.y);
      pk.y = pkh(v.z, v.w);
      *(uint2*)&prebase[(size_t)o * HW_ + px4] = pk;
    }
  }
}

// ---------------- K4: finalize stats from per-tile partials ----------------
__global__ __launch_bounds__(256) void k4_fin(const float* __restrict__ pstats2,
                                              float* __restrict__ stats) {
  const int pl = blockIdx.x;  // 0..127 = b*O + o
  const int b = pl >> 6, o = pl & 63;
  const float2* src = (const float2*)pstats2 + (size_t)b * 576 * 64 + o;
  float s = 0.f, s2 = 0.f;
  for (int tt = threadIdx.x; tt < 576; tt += 256) {
    const float2 v = src[(size_t)tt * 64];
    s += v.x;
    s2 += v.y;
  }
#pragma unroll
  for (int m = 1; m < 64; m <<= 1) {
    s += __shfl_xor(s, m);
    s2 += __shfl_xor(s2, m);
  }
  __shared__ float ls[4], ls2[4];
  const int wid = threadIdx.x >> 6;
  if ((threadIdx.x & 63) == 0) { ls[wid] = s; ls2[wid] = s2; }
  __syncthreads();
  if (threadIdx.x == 0) {
    const float ts = ls[0] + ls[1] + ls[2] + ls[3];
    const float ts2 = ls2[0] + ls2[1] + ls2[2] + ls2[3];
    const float inv = 1.f / (float)HW_;
    const float mu = ts * inv;
    const float var = fmaxf(fmaf(-mu, mu, ts2 * inv), 0.f);
    stats[pl * 2] = mu;
    stats[pl * 2 + 1] = rsqrtf(var + EPS_);
  }
}

// ---------------- K5: apply instance norm + ReLU (fp16 in, fp32 out) ----------
__global__ __launch_bounds__(256) void k5_norm(const unsigned short* __restrict__ pre16,
                                               const float* __restrict__ stats,
                                               float* __restrict__ out) {
  const int i4 = blockIdx.x * 256 + threadIdx.x;  // 4-px unit
  const int plane = i4 / 9216;
  const float mu = stats[plane * 2];
  const float rs = stats[plane * 2 + 1];
  const uint2 pk = ((const uint2*)pre16)[i4];
  const __half2 h0 = *(const __half2*)&pk.x;
  const __half2 h1 = *(const __half2*)&pk.y;
  const float2 f0 = __half22float2(h0);
  const float2 f1 = __half22float2(h1);
  float4 v;
  v.x = fmaxf((f0.x - mu) * rs, 0.f);
  v.y = fmaxf((f0.y - mu) * rs, 0.f);
  v.z = fmaxf((f1.x - mu) * rs, 0.f);
  v.w = fmaxf((f1.y - mu) * rs, 0.f);
  ((float4*)out)[i4] = v;
}

extern "C" void kernel_launch(void* const* d_in, const int* in_sizes, int n_in,
                              void* d_out, int out_size, void* d_ws, size_t ws_size,
                              hipStream_t stream) {
  const float* x = (const float*)d_in[0];
  const float* dw_w = (const float*)d_in[1];
  const float* dw_b = (const float*)d_in[2];
  const float* bn_g = (const float*)d_in[3];
  const float* bn_b = (const float*)d_in[4];
  const float* bn_m = (const float*)d_in[5];
  const float* bn_v = (const float*)d_in[6];
  const float* pw_w = (const float*)d_in[7];
  const float* pw_b = (const float*)d_in[8];
  const float* dcn_w = (const float*)d_in[9];
  float* out = (float*)d_out;

  // workspace layout (floats)
  float* ws = (float*)d_ws;
  float* h = ws;                                   // B*C*HW fp32 = 4718592 floats
  float4* om4 = (float4*)(h + (size_t)B_ * C_ * HW_);  // B*9*HW float4 = 2654208 floats
  unsigned short* pre16 = (unsigned short*)((float*)om4 + (size_t)B_ * 9 * HW_ * 4);  // B*O*HW fp16
  unsigned short* wT2 = pre16 + (size_t)B_ * O_ * HW_;  // 36864 u16
  float* stats = (float*)(wT2 + (size_t)K_ * O_ * C_);  // 256
  if (ws_size < (size_t)(4718592 + 2654208 + 2359296 + 9216 + 256) * sizeof(float)) return;
  // xR (gather-layout fp16, 9.4 MB) + pstats2 (590 KB) live in d_out:
  // both dead before k5 overwrites d_out.
  unsigned short* xR = (unsigned short*)d_out;
  float* pstats2 = (float*)d_out + 2359296;  // after xR

  k0_wt<<<dim3(144), dim3(256), 0, stream>>>(dcn_w, wT2);
  k1b_t<<<dim3(HW_ / 256, B_), dim3(256), 0, stream>>>(x, xR);
  k1_dw<<<dim3(HW_ / 256, B_ * C_), dim3(256), 0, stream>>>(x, dw_w, dw_b, bn_g, bn_b,
                                                            bn_m, bn_v, h);
  k2_pw<<<dim3(HW_ / 256, B_), dim3(256), 0, stream>>>(h, pw_w, pw_b, om4);
  k3_dcn<<<dim3(B_ * HW_ / 64), dim3(256), 0, stream>>>(xR, om4, wT2, pre16, pstats2);
  k4_fin<<<dim3(B_ * O_), dim3(256), 0, stream>>>(pstats2, stats);
  k5_norm<<<dim3(B_ * O_ * HW_ / 4 / 256), dim3(256), 0, stream>>>(pre16, stats, out);
}

// Round 12
// 94.149 us; speedup vs baseline: 1.2783x; 1.0959x over previous
//
#include <hip/hip_runtime.h>
#include <hip/hip_fp16.h>
#include <math.h>

#define H_ 192
#define W_ 192
#define HW_ 36864
#define C_ 64
#define O_ 64
#define B_ 2
#define K_ 9
#define EPS_ 1e-5f

typedef __attribute__((ext_vector_type(8))) _Float16 f16x8;  // 8 fp16 = 4 VGPR
typedef __attribute__((ext_vector_type(4))) float f32x4;

union U16B { uint4 u; __half2 h[4]; };

__device__ __forceinline__ unsigned int pkh(float lo, float hi) {
  return (unsigned int)__half_as_ushort(__float2half(lo)) |
         ((unsigned int)__half_as_ushort(__float2half(hi)) << 16);
}

// ---------------- K_front: k1 (dw+BN+ReLU -> h16) ∥ k1b (x->xR) ∥ k0 (w->wT2) ---
// blockIdx.y: [0,128) = k1 planes; 128/129 = k1b (b=y-128); 130 = k0.
// Branch is block-uniform -> no divergence; independent work co-schedules.
__global__ __launch_bounds__(256) void k_front(const float* __restrict__ x,
                                               const float* __restrict__ dw_w,
                                               const float* __restrict__ dw_b,
                                               const float* __restrict__ bn_g,
                                               const float* __restrict__ bn_b,
                                               const float* __restrict__ bn_m,
                                               const float* __restrict__ bn_v,
                                               const float* __restrict__ dcn_w,
                                               unsigned short* __restrict__ h16,
                                               unsigned short* __restrict__ xR,
                                               unsigned short* __restrict__ wT2) {
  const int ybl = blockIdx.y;
  const int tid = threadIdx.x;
  if (ybl < 128) {
    // ---- k1: depthwise 3x3 + bias + BN + ReLU, fp16 output
    const int plane = ybl;                 // b*C + c
    const int c = plane & (C_ - 1);
    const int p = blockIdx.x * 256 + tid;
    const int y = p / W_;
    const int xx = p - y * W_;
    const float* xp = x + (size_t)plane * HW_;
    float w[9];
#pragma unroll
    for (int i = 0; i < 9; ++i) w[i] = dw_w[c * 9 + i];
    float s = 0.f;
#pragma unroll
    for (int dy = 0; dy < 3; ++dy) {
      const int yy = y + dy - 1;
      if (yy < 0 || yy >= H_) continue;
#pragma unroll
      for (int dx = 0; dx < 3; ++dx) {
        const int xc = xx + dx - 1;
        if (xc < 0 || xc >= W_) continue;
        s = fmaf(w[dy * 3 + dx], xp[yy * W_ + xc], s);
      }
    }
    const float scale = bn_g[c] * rsqrtf(bn_v[c] + EPS_);
    const float shift = fmaf(dw_b[c] - bn_m[c], scale, bn_b[c]);
    const float hv = fmaxf(fmaf(s, scale, shift), 0.f);
    h16[(size_t)plane * HW_ + p] = __half_as_ushort(__float2half(hv));
  } else if (ybl < 130) {
    // ---- k1b: x NCHW fp32 -> xR[b][y][cg][x][8ch] fp16
    const int b = ybl - 128;
    const int p = blockIdx.x * 256 + tid;
    const int y = p / W_;
    const int xx = p - y * W_;
    const float* xp = x + (size_t)b * C_ * HW_ + p;
    uint4* dst = (uint4*)xR + (size_t)b * HW_ * 8;
#pragma unroll
    for (int cc = 0; cc < 8; ++cc) {
      uint4 u;
      u.x = pkh(xp[(size_t)(cc * 8 + 0) * HW_], xp[(size_t)(cc * 8 + 1) * HW_]);
      u.y = pkh(xp[(size_t)(cc * 8 + 2) * HW_], xp[(size_t)(cc * 8 + 3) * HW_]);
      u.z = pkh(xp[(size_t)(cc * 8 + 4) * HW_], xp[(size_t)(cc * 8 + 5) * HW_]);
      u.w = pkh(xp[(size_t)(cc * 8 + 6) * HW_], xp[(size_t)(cc * 8 + 7) * HW_]);
      dst[(y * 8 + cc) * W_ + xx] = u;
    }
  } else {
    // ---- k0: dcn_w (O,C,3,3) fp32 -> wT2[k][o][c] fp16
    const int i = blockIdx.x * 256 + tid;  // (o*C + c)*9 + k
    const int o = i / (C_ * 9);
    const int rem = i - o * (C_ * 9);
    const int c = rem / 9;
    const int kk = rem - c * 9;
    wT2[((size_t)(kk * O_) + o) * C_ + c] = __half_as_ushort(__float2half(dcn_w[i]));
  }
}

// ---------------- K2: pointwise 64->27 per pixel (h fp16 in), om4 epilogue -----
// om4[b][k][px] = {dy + (ky-1), dx + (kx-1), sigmoid(mask), 0}
__global__ __launch_bounds__(256) void k2_pw(const unsigned short* __restrict__ h16,
                                             const float* __restrict__ pw_w,
                                             const float* __restrict__ pw_b,
                                             float4* __restrict__ om4) {
  __shared__ float wl[C_ * 28];
  const int b = blockIdx.y;
  const int p = blockIdx.x * 256 + threadIdx.x;
  for (int i = threadIdx.x; i < C_ * 28; i += 256) {
    const int c = i / 28, j = i - c * 28;
    wl[i] = (j < 27) ? pw_w[j * C_ + c] : 0.f;
  }
  __syncthreads();
  float s[27];
#pragma unroll
  for (int j = 0; j < 27; ++j) s[j] = 0.f;
  const unsigned short* hp = h16 + (size_t)b * C_ * HW_ + p;
  for (int c = 0; c < C_; ++c) {
    const float hv = __half2float(__ushort_as_half(hp[(size_t)c * HW_]));
    float wv[28];
#pragma unroll
    for (int q = 0; q < 7; ++q)
      *(float4*)&wv[q * 4] = *(const float4*)&wl[c * 28 + q * 4];
#pragma unroll
    for (int j = 0; j < 27; ++j) s[j] = fmaf(hv, wv[j], s[j]);
  }
  float4* op = om4 + (size_t)b * 9 * HW_;
#pragma unroll
  for (int k = 0; k < 9; ++k) {
    const float ry = (float)(k / 3 - 1), rx = (float)(k % 3 - 1);
    float4 v;
    v.x = s[2 * k] + pw_b[2 * k] + ry;
    v.y = s[2 * k + 1] + pw_b[2 * k + 1] + rx;
    v.z = 1.f / (1.f + __expf(-(s[18 + k] + pw_b[18 + k])));
    v.w = 0.f;
    op[(size_t)k * HW_ + p] = v;
  }
}

// ---------------- K3: fused deformable gather (fp16 pk) + MFMA f16 contraction --
// 64-px tile, 64 o, 256 threads (4 waves). Wave cq: channel-groups {cq,cq+4},
// o-strip cq*16. Interp fully packed fp16 (__hfma2). Output pre16 (fp16).
__global__ __launch_bounds__(256, 4) void k3_dcn(const unsigned short* __restrict__ xR,
                                                 const float4* __restrict__ om4,
                                                 const unsigned short* __restrict__ wT2,
                                                 unsigned short* __restrict__ pre16,
                                                 float* __restrict__ pstats2) {
  __shared__ __align__(16) unsigned short smem[8192];  // 16 KB, dual-use
  unsigned short* wlds = smem;         // [o][c] fp16 swz, 8 KB
  unsigned short* vlds = smem + 4096;  // [px][c] fp16 swz, 8 KB

  const int tid = threadIdx.x;
  // bijective XCD swizzle: 1152 blocks = 8 XCD x 144 contiguous tiles
  const int t = (blockIdx.x & 7) * 144 + (blockIdx.x >> 3);
  const int b = t / 576;
  const int p0 = (t - b * 576) * 64;
  const uint4* xr = (const uint4*)xR + (size_t)b * HW_ * 8;
  const float4* omb = om4 + (size_t)b * 9 * HW_;

  const int pxi = tid & 63;   // gather pixel
  const int cq = tid >> 6;    // wave id == channel-group slot == o-strip/16
  const int lr = pxi & 15;    // lane&15
  const int lg = pxi >> 4;    // lane>>4 (k-group)
  const int oo0 = cq * 16;

  const int p = p0 + pxi;
  const int y = p / W_;
  const int xx = p - y * W_;

  f32x4 acc[4];
#pragma unroll
  for (int j = 0; j < 4; ++j) acc[j] = (f32x4){0.f, 0.f, 0.f, 0.f};

  for (int k = 0; k < K_; ++k) {
    // --- issue w-stage loads early (L1/L2-resident, 2 x 16B per thread)
    const uint4* wsrc = (const uint4*)(wT2 + (k << 12));
    const uint4 wv0 = wsrc[tid];
    const uint4 wv1 = wsrc[tid + 256];
    // --- packed coords: one float4 per tap (ky/kx + bias + sigmoid pre-folded)
    const float4 od = omb[(size_t)k * HW_ + p];
    const float py = (float)y + od.x;
    const float pxf = (float)xx + od.y;
    const float mk = od.z;
    const float y0f = floorf(py), x0f = floorf(pxf);
    const float wy1 = py - y0f, wx1 = pxf - x0f;
    const float wy0 = 1.f - wy1, wx0 = 1.f - wx1;
    const int y0 = (int)y0f, x0i = (int)x0f;
    const int y1 = y0 + 1, x1i = x0i + 1;
    const bool vy0 = (y0 >= 0) & (y0 < H_);
    const bool vy1 = (y1 >= 0) & (y1 < H_);
    const bool vx0 = (x0i >= 0) & (x0i < W_);
    const bool vx1 = (x1i >= 0) & (x1i < W_);
    const int yc0 = min(max(y0, 0), H_ - 1), yc1 = min(max(y1, 0), H_ - 1);
    const int xc0 = min(max(x0i, 0), W_ - 1), xc1 = min(max(x1i, 0), W_ - 1);
    const float g0 = (vy0 & vx0) ? wy0 * wx0 * mk : 0.f;
    const float g1 = (vy0 & vx1) ? wy0 * wx1 * mk : 0.f;
    const float g2 = (vy1 & vx0) ? wy1 * wx0 * mk : 0.f;
    const float g3 = (vy1 & vx1) ? wy1 * wx1 * mk : 0.f;

    // --- x-coherent gather: 8 x 16B loads (4 corners x 2 channel-groups)
    const int ry0 = yc0 * (8 * W_), ry1 = yc1 * (8 * W_);
    const int ca = cq * W_, cb = (cq + 4) * W_;
    U16B a0, a1, a2, a3, b0v, b1v, b2v, b3v;
    a0.u = xr[ry0 + ca + xc0];  b0v.u = xr[ry0 + cb + xc0];
    a1.u = xr[ry0 + ca + xc1];  b1v.u = xr[ry0 + cb + xc1];
    a2.u = xr[ry1 + ca + xc0];  b2v.u = xr[ry1 + cb + xc0];
    a3.u = xr[ry1 + ca + xc1];  b3v.u = xr[ry1 + cb + xc1];

    // --- packed fp16 interpolation: 32 x v_pk_fma_f16, no unpack/repack
    const __half2 g0h = __float2half2_rn(g0);
    const __half2 g1h = __float2half2_rn(g1);
    const __half2 g2h = __float2half2_rn(g2);
    const __half2 g3h = __float2half2_rn(g3);
    U16B va, vb;
    va.u = make_uint4(0, 0, 0, 0);
    vb.u = make_uint4(0, 0, 0, 0);
#pragma unroll
    for (int i = 0; i < 4; ++i) {
      va.h[i] = __hfma2(a0.h[i], g0h, va.h[i]);
      vb.h[i] = __hfma2(b0v.h[i], g0h, vb.h[i]);
      va.h[i] = __hfma2(a1.h[i], g1h, va.h[i]);
      vb.h[i] = __hfma2(b1v.h[i], g1h, vb.h[i]);
      va.h[i] = __hfma2(a2.h[i], g2h, va.h[i]);
      vb.h[i] = __hfma2(b2v.h[i], g2h, vb.h[i]);
      va.h[i] = __hfma2(a3.h[i], g3h, va.h[i]);
      vb.h[i] = __hfma2(b3v.h[i], g3h, vb.h[i]);
    }

    __syncthreads();  // (A) all waves done MFMA-reading previous tap's LDS
    // --- stage w tap (swizzled 16B blocks): block index i -> row i>>3, blk i&7
    {
      const int r0 = tid >> 3, b0i = tid & 7;
      ((uint4*)wlds)[(r0 << 3) + (b0i ^ (r0 & 7))] = wv0;
      const int r1 = (tid + 256) >> 3;
      ((uint4*)wlds)[(r1 << 3) + (b0i ^ (r1 & 7))] = wv1;
    }
    // --- write vlds rows (already packed fp16; swizzled)
    {
      const int rsw = pxi & 7;
      ((uint4*)vlds)[(pxi << 3) + (cq ^ rsw)] = va.u;
      ((uint4*)vlds)[(pxi << 3) + ((cq + 4) ^ rsw)] = vb.u;
    }
    __syncthreads();  // (B) wlds + vlds ready
    // --- MFMA: D[o-strip 16][px 64] += w[o][c] * val[c][px], K=64 in 2 steps
#pragma unroll
    for (int ks = 0; ks < 2; ++ks) {
      const int kb = (ks << 2) + lg;
      const int ra = oo0 + lr;
      const f16x8 afr = *(const f16x8*)&((const uint4*)wlds)[(ra << 3) + (kb ^ (ra & 7))];
#pragma unroll
      for (int j = 0; j < 4; ++j) {
        const int rb = (j << 4) + lr;
        const f16x8 bfr = *(const f16x8*)&((const uint4*)vlds)[(rb << 3) + (kb ^ (rb & 7))];
        acc[j] = __builtin_amdgcn_mfma_f32_16x16x32_f16(afr, bfr, acc[j], 0, 0, 0);
      }
    }
  }

  // --- per-block IN partial stats (register-only; no atomics; deterministic)
#pragma unroll
  for (int q = 0; q < 4; ++q) {
    float s = acc[0][q] + acc[1][q] + acc[2][q] + acc[3][q];
    float s2 = fmaf(acc[0][q], acc[0][q],
               fmaf(acc[1][q], acc[1][q],
               fmaf(acc[2][q], acc[2][q], acc[3][q] * acc[3][q])));
#pragma unroll
    for (int m = 1; m < 16; m <<= 1) {
      s += __shfl_xor(s, m);
      s2 += __shfl_xor(s2, m);
    }
    if (lr == 0) {
      const int pll = oo0 + (lg << 2) + q;
      ((float2*)pstats2)[(size_t)t * 64 + pll] = make_float2(s, s2);
    }
  }

  // --- epilogue: transpose through (now dead) LDS -> coalesced fp16 stores
  __syncthreads();  // all MFMA reads of smem done
  float* fsm = (float*)smem;  // [64 o][64 px] f32 = 16 KB
#pragma unroll
  for (int j = 0; j < 4; ++j)
#pragma unroll
    for (int q = 0; q < 4; ++q)
      fsm[(oo0 + (lg << 2) + q) * 64 + (j << 4) + lr] = acc[j][q];
  __syncthreads();
  {
    const float4* fsm4 = (const float4*)fsm;
    unsigned short* prebase = pre16 + (size_t)b * O_ * HW_ + p0;
#pragma unroll
    for (int i = 0; i < 4; ++i) {
      const int f = tid + (i << 8);
      const int o = f >> 4;
      const int px4 = (f & 15) << 2;
      const float4 v = fsm4[f];
      uint2 pk;
      pk.x = pkh(v.x, v.y);
      pk.y = pkh(v.z, v.w);
      *(uint2*)&prebase[(size_t)o * HW_ + px4] = pk;
    }
  }
}

// ---------------- K4: finalize stats from per-tile partials ----------------
__global__ __launch_bounds__(256) void k4_fin(const float* __restrict__ pstats2,
                                              float* __restrict__ stats) {
  const int pl = blockIdx.x;  // 0..127 = b*O + o
  const int b = pl >> 6, o = pl & 63;
  const float2* src = (const float2*)pstats2 + (size_t)b * 576 * 64 + o;
  float s = 0.f, s2 = 0.f;
  for (int tt = threadIdx.x; tt < 576; tt += 256) {
    const float2 v = src[(size_t)tt * 64];
    s += v.x;
    s2 += v.y;
  }
#pragma unroll
  for (int m = 1; m < 64; m <<= 1) {
    s += __shfl_xor(s, m);
    s2 += __shfl_xor(s2, m);
  }
  __shared__ float ls[4], ls2[4];
  const int wid = threadIdx.x >> 6;
  if ((threadIdx.x & 63) == 0) { ls[wid] = s; ls2[wid] = s2; }
  __syncthreads();
  if (threadIdx.x == 0) {
    const float ts = ls[0] + ls[1] + ls[2] + ls[3];
    const float ts2 = ls2[0] + ls2[1] + ls2[2] + ls2[3];
    const float inv = 1.f / (float)HW_;
    const float mu = ts * inv;
    const float var = fmaxf(fmaf(-mu, mu, ts2 * inv), 0.f);
    stats[pl * 2] = mu;
    stats[pl * 2 + 1] = rsqrtf(var + EPS_);
  }
}

// ---------------- K5: apply instance norm + ReLU (fp16 in, fp32 out) ----------
__global__ __launch_bounds__(256) void k5_norm(const unsigned short* __restrict__ pre16,
                                               const float* __restrict__ stats,
                                               float* __restrict__ out) {
  const int i4 = blockIdx.x * 256 + threadIdx.x;  // 4-px unit
  const int plane = i4 / 9216;
  const float mu = stats[plane * 2];
  const float rs = stats[plane * 2 + 1];
  const uint2 pk = ((const uint2*)pre16)[i4];
  const __half2 h0 = *(const __half2*)&pk.x;
  const __half2 h1 = *(const __half2*)&pk.y;
  const float2 f0 = __half22float2(h0);
  const float2 f1 = __half22float2(h1);
  float4 v;
  v.x = fmaxf((f0.x - mu) * rs, 0.f);
  v.y = fmaxf((f0.y - mu) * rs, 0.f);
  v.z = fmaxf((f1.x - mu) * rs, 0.f);
  v.w = fmaxf((f1.y - mu) * rs, 0.f);
  ((float4*)out)[i4] = v;
}

extern "C" void kernel_launch(void* const* d_in, const int* in_sizes, int n_in,
                              void* d_out, int out_size, void* d_ws, size_t ws_size,
                              hipStream_t stream) {
  const float* x = (const float*)d_in[0];
  const float* dw_w = (const float*)d_in[1];
  const float* dw_b = (const float*)d_in[2];
  const float* bn_g = (const float*)d_in[3];
  const float* bn_b = (const float*)d_in[4];
  const float* bn_m = (const float*)d_in[5];
  const float* bn_v = (const float*)d_in[6];
  const float* pw_w = (const float*)d_in[7];
  const float* pw_b = (const float*)d_in[8];
  const float* dcn_w = (const float*)d_in[9];
  float* out = (float*)d_out;

  // workspace layout
  unsigned short* h16 = (unsigned short*)d_ws;               // B*C*HW fp16 = 4.7 MB
  float4* om4 = (float4*)(h16 + (size_t)B_ * C_ * HW_);      // B*9*HW float4 = 10.6 MB
  unsigned short* pre16 = (unsigned short*)(om4 + (size_t)B_ * 9 * HW_);  // 4.7 MB
  unsigned short* wT2 = pre16 + (size_t)B_ * O_ * HW_;       // 72 KB
  float* stats = (float*)(wT2 + (size_t)K_ * O_ * C_);       // 1 KB
  if (ws_size < (size_t)(4718592 + 10616832 + 4718592 + 73728 + 1024)) return;
  // xR (gather-layout fp16, 9.4 MB) + pstats2 (590 KB) live in d_out:
  // both dead before k5 overwrites d_out.
  unsigned short* xR = (unsigned short*)d_out;
  float* pstats2 = (float*)d_out + 2359296;  // after xR

  k_front<<<dim3(HW_ / 256, 131), dim3(256), 0, stream>>>(x, dw_w, dw_b, bn_g, bn_b,
                                                          bn_m, bn_v, dcn_w,
                                                          h16, xR, wT2);
  k2_pw<<<dim3(HW_ / 256, B_), dim3(256), 0, stream>>>(h16, pw_w, pw_b, om4);
  k3_dcn<<<dim3(B_ * HW_ / 64), dim3(256), 0, stream>>>(xR, om4, wT2, pre16, pstats2);
  k4_fin<<<dim3(B_ * O_), dim3(256), 0, stream>>>(pstats2, stats);
  k5_norm<<<dim3(B_ * O_ * HW_ / 4 / 256), dim3(256), 0, stream>>>(pre16, stats, out);
}

// Round 13
// 91.802 us; speedup vs baseline: 1.3109x; 1.0256x over previous
//
#include <hip/hip_runtime.h>
#include <hip/hip_fp16.h>
#include <math.h>

#define H_ 192
#define W_ 192
#define HW_ 36864
#define C_ 64
#define O_ 64
#define B_ 2
#define K_ 9
#define EPS_ 1e-5f

typedef __attribute__((ext_vector_type(8))) _Float16 f16x8;  // 8 fp16 = 4 VGPR
typedef __attribute__((ext_vector_type(4))) float f32x4;

union U16B { uint4 u; __half2 h[4]; };

__device__ __forceinline__ unsigned int pkh(float lo, float hi) {
  return (unsigned int)__half_as_ushort(__float2half(lo)) |
         ((unsigned int)__half_as_ushort(__float2half(hi)) << 16);
}

// ---------------- K_front: k1 (dw+BN+ReLU -> h16) ∥ k1b (x->xR) ∥ k0 (w->wT2) ---
// blockIdx.y: [0,128) = k1 planes; 128/129 = k1b (b=y-128); 130 = k0.
// Branch is block-uniform -> no divergence; independent work co-schedules.
__global__ __launch_bounds__(256) void k_front(const float* __restrict__ x,
                                               const float* __restrict__ dw_w,
                                               const float* __restrict__ dw_b,
                                               const float* __restrict__ bn_g,
                                               const float* __restrict__ bn_b,
                                               const float* __restrict__ bn_m,
                                               const float* __restrict__ bn_v,
                                               const float* __restrict__ dcn_w,
                                               unsigned short* __restrict__ h16,
                                               unsigned short* __restrict__ xR,
                                               unsigned short* __restrict__ wT2) {
  const int ybl = blockIdx.y;
  const int tid = threadIdx.x;
  if (ybl < 128) {
    // ---- k1: depthwise 3x3 + bias + BN + ReLU, fp16 output
    const int plane = ybl;                 // b*C + c
    const int c = plane & (C_ - 1);
    const int p = blockIdx.x * 256 + tid;
    const int y = p / W_;
    const int xx = p - y * W_;
    const float* xp = x + (size_t)plane * HW_;
    float w[9];
#pragma unroll
    for (int i = 0; i < 9; ++i) w[i] = dw_w[c * 9 + i];
    float s = 0.f;
#pragma unroll
    for (int dy = 0; dy < 3; ++dy) {
      const int yy = y + dy - 1;
      if (yy < 0 || yy >= H_) continue;
#pragma unroll
      for (int dx = 0; dx < 3; ++dx) {
        const int xc = xx + dx - 1;
        if (xc < 0 || xc >= W_) continue;
        s = fmaf(w[dy * 3 + dx], xp[yy * W_ + xc], s);
      }
    }
    const float scale = bn_g[c] * rsqrtf(bn_v[c] + EPS_);
    const float shift = fmaf(dw_b[c] - bn_m[c], scale, bn_b[c]);
    const float hv = fmaxf(fmaf(s, scale, shift), 0.f);
    h16[(size_t)plane * HW_ + p] = __half_as_ushort(__float2half(hv));
  } else if (ybl < 130) {
    // ---- k1b: x NCHW fp32 -> xR[b][y][cg][x][8ch] fp16
    const int b = ybl - 128;
    const int p = blockIdx.x * 256 + tid;
    const int y = p / W_;
    const int xx = p - y * W_;
    const float* xp = x + (size_t)b * C_ * HW_ + p;
    uint4* dst = (uint4*)xR + (size_t)b * HW_ * 8;
#pragma unroll
    for (int cc = 0; cc < 8; ++cc) {
      uint4 u;
      u.x = pkh(xp[(size_t)(cc * 8 + 0) * HW_], xp[(size_t)(cc * 8 + 1) * HW_]);
      u.y = pkh(xp[(size_t)(cc * 8 + 2) * HW_], xp[(size_t)(cc * 8 + 3) * HW_]);
      u.z = pkh(xp[(size_t)(cc * 8 + 4) * HW_], xp[(size_t)(cc * 8 + 5) * HW_]);
      u.w = pkh(xp[(size_t)(cc * 8 + 6) * HW_], xp[(size_t)(cc * 8 + 7) * HW_]);
      dst[(y * 8 + cc) * W_ + xx] = u;
    }
  } else {
    // ---- k0: dcn_w (O,C,3,3) fp32 -> wT2[k][o][c] fp16
    const int i = blockIdx.x * 256 + tid;  // (o*C + c)*9 + k
    const int o = i / (C_ * 9);
    const int rem = i - o * (C_ * 9);
    const int c = rem / 9;
    const int kk = rem - c * 9;
    wT2[((size_t)(kk * O_) + o) * C_ + c] = __half_as_ushort(__float2half(dcn_w[i]));
  }
}

// ---------------- K2: pointwise 64->27 per pixel (h fp16 in), om4 epilogue -----
// om4[b][k][px] = {dy + (ky-1), dx + (kx-1), sigmoid(mask), 0}
__global__ __launch_bounds__(256) void k2_pw(const unsigned short* __restrict__ h16,
                                             const float* __restrict__ pw_w,
                                             const float* __restrict__ pw_b,
                                             float4* __restrict__ om4) {
  __shared__ float wl[C_ * 28];
  const int b = blockIdx.y;
  const int p = blockIdx.x * 256 + threadIdx.x;
  for (int i = threadIdx.x; i < C_ * 28; i += 256) {
    const int c = i / 28, j = i - c * 28;
    wl[i] = (j < 27) ? pw_w[j * C_ + c] : 0.f;
  }
  __syncthreads();
  float s[27];
#pragma unroll
  for (int j = 0; j < 27; ++j) s[j] = 0.f;
  const unsigned short* hp = h16 + (size_t)b * C_ * HW_ + p;
  for (int c = 0; c < C_; ++c) {
    const float hv = __half2float(__ushort_as_half(hp[(size_t)c * HW_]));
    float wv[28];
#pragma unroll
    for (int q = 0; q < 7; ++q)
      *(float4*)&wv[q * 4] = *(const float4*)&wl[c * 28 + q * 4];
#pragma unroll
    for (int j = 0; j < 27; ++j) s[j] = fmaf(hv, wv[j], s[j]);
  }
  float4* op = om4 + (size_t)b * 9 * HW_;
#pragma unroll
  for (int k = 0; k < 9; ++k) {
    const float ry = (float)(k / 3 - 1), rx = (float)(k % 3 - 1);
    float4 v;
    v.x = s[2 * k] + pw_b[2 * k] + ry;
    v.y = s[2 * k + 1] + pw_b[2 * k + 1] + rx;
    v.z = 1.f / (1.f + __expf(-(s[18 + k] + pw_b[18 + k])));
    v.w = 0.f;
    op[(size_t)k * HW_ + p] = v;
  }
}

// ---------------- K3: fused deformable gather (fp16 pk) + MFMA f16 contraction --
// 64-px tile, 64 o, 256 threads (4 waves). Wave cq: channel-groups {cq,cq+4},
// o-strip cq*16. Interp fully packed fp16 (__hfma2). Output pre16 (fp16).
__global__ __launch_bounds__(256, 4) void k3_dcn(const unsigned short* __restrict__ xR,
                                                 const float4* __restrict__ om4,
                                                 const unsigned short* __restrict__ wT2,
                                                 unsigned short* __restrict__ pre16,
                                                 float* __restrict__ pstats2) {
  __shared__ __align__(16) unsigned short smem[8192];  // 16 KB, dual-use
  unsigned short* wlds = smem;         // [o][c] fp16 swz, 8 KB
  unsigned short* vlds = smem + 4096;  // [px][c] fp16 swz, 8 KB

  const int tid = threadIdx.x;
  // bijective XCD swizzle: 1152 blocks = 8 XCD x 144 contiguous tiles
  const int t = (blockIdx.x & 7) * 144 + (blockIdx.x >> 3);
  const int b = t / 576;
  const int p0 = (t - b * 576) * 64;
  const uint4* xr = (const uint4*)xR + (size_t)b * HW_ * 8;
  const float4* omb = om4 + (size_t)b * 9 * HW_;

  const int pxi = tid & 63;   // gather pixel
  const int cq = tid >> 6;    // wave id == channel-group slot == o-strip/16
  const int lr = pxi & 15;    // lane&15
  const int lg = pxi >> 4;    // lane>>4 (k-group)
  const int oo0 = cq * 16;

  const int p = p0 + pxi;
  const int y = p / W_;
  const int xx = p - y * W_;

  f32x4 acc[4];
#pragma unroll
  for (int j = 0; j < 4; ++j) acc[j] = (f32x4){0.f, 0.f, 0.f, 0.f};

  for (int k = 0; k < K_; ++k) {
    // --- issue w-stage loads early (L1/L2-resident, 2 x 16B per thread)
    const uint4* wsrc = (const uint4*)(wT2 + (k << 12));
    const uint4 wv0 = wsrc[tid];
    const uint4 wv1 = wsrc[tid + 256];
    // --- packed coords: one float4 per tap (ky/kx + bias + sigmoid pre-folded)
    const float4 od = omb[(size_t)k * HW_ + p];
    const float py = (float)y + od.x;
    const float pxf = (float)xx + od.y;
    const float mk = od.z;
    const float y0f = floorf(py), x0f = floorf(pxf);
    const float wy1 = py - y0f, wx1 = pxf - x0f;
    const float wy0 = 1.f - wy1, wx0 = 1.f - wx1;
    const int y0 = (int)y0f, x0i = (int)x0f;
    const int y1 = y0 + 1, x1i = x0i + 1;
    const bool vy0 = (y0 >= 0) & (y0 < H_);
    const bool vy1 = (y1 >= 0) & (y1 < H_);
    const bool vx0 = (x0i >= 0) & (x0i < W_);
    const bool vx1 = (x1i >= 0) & (x1i < W_);
    const int yc0 = min(max(y0, 0), H_ - 1), yc1 = min(max(y1, 0), H_ - 1);
    const int xc0 = min(max(x0i, 0), W_ - 1), xc1 = min(max(x1i, 0), W_ - 1);
    const float g0 = (vy0 & vx0) ? wy0 * wx0 * mk : 0.f;
    const float g1 = (vy0 & vx1) ? wy0 * wx1 * mk : 0.f;
    const float g2 = (vy1 & vx0) ? wy1 * wx0 * mk : 0.f;
    const float g3 = (vy1 & vx1) ? wy1 * wx1 * mk : 0.f;

    // --- x-coherent gather: 8 x 16B loads (4 corners x 2 channel-groups)
    const int ry0 = yc0 * (8 * W_), ry1 = yc1 * (8 * W_);
    const int ca = cq * W_, cb = (cq + 4) * W_;
    U16B a0, a1, a2, a3, b0v, b1v, b2v, b3v;
    a0.u = xr[ry0 + ca + xc0];  b0v.u = xr[ry0 + cb + xc0];
    a1.u = xr[ry0 + ca + xc1];  b1v.u = xr[ry0 + cb + xc1];
    a2.u = xr[ry1 + ca + xc0];  b2v.u = xr[ry1 + cb + xc0];
    a3.u = xr[ry1 + ca + xc1];  b3v.u = xr[ry1 + cb + xc1];

    // --- packed fp16 interpolation: 32 x v_pk_fma_f16, no unpack/repack
    const __half2 g0h = __float2half2_rn(g0);
    const __half2 g1h = __float2half2_rn(g1);
    const __half2 g2h = __float2half2_rn(g2);
    const __half2 g3h = __float2half2_rn(g3);
    U16B va, vb;
    va.u = make_uint4(0, 0, 0, 0);
    vb.u = make_uint4(0, 0, 0, 0);
#pragma unroll
    for (int i = 0; i < 4; ++i) {
      va.h[i] = __hfma2(a0.h[i], g0h, va.h[i]);
      vb.h[i] = __hfma2(b0v.h[i], g0h, vb.h[i]);
      va.h[i] = __hfma2(a1.h[i], g1h, va.h[i]);
      vb.h[i] = __hfma2(b1v.h[i], g1h, vb.h[i]);
      va.h[i] = __hfma2(a2.h[i], g2h, va.h[i]);
      vb.h[i] = __hfma2(b2v.h[i], g2h, vb.h[i]);
      va.h[i] = __hfma2(a3.h[i], g3h, va.h[i]);
      vb.h[i] = __hfma2(b3v.h[i], g3h, vb.h[i]);
    }

    __syncthreads();  // (A) all waves done MFMA-reading previous tap's LDS
    // --- stage w tap (swizzled 16B blocks): block index i -> row i>>3, blk i&7
    {
      const int r0 = tid >> 3, b0i = tid & 7;
      ((uint4*)wlds)[(r0 << 3) + (b0i ^ (r0 & 7))] = wv0;
      const int r1 = (tid + 256) >> 3;
      ((uint4*)wlds)[(r1 << 3) + (b0i ^ (r1 & 7))] = wv1;
    }
    // --- write vlds rows (already packed fp16; swizzled)
    {
      const int rsw = pxi & 7;
      ((uint4*)vlds)[(pxi << 3) + (cq ^ rsw)] = va.u;
      ((uint4*)vlds)[(pxi << 3) + ((cq + 4) ^ rsw)] = vb.u;
    }
    __syncthreads();  // (B) wlds + vlds ready
    // --- MFMA: D[o-strip 16][px 64] += w[o][c] * val[c][px], K=64 in 2 steps
#pragma unroll
    for (int ks = 0; ks < 2; ++ks) {
      const int kb = (ks << 2) + lg;
      const int ra = oo0 + lr;
      const f16x8 afr = *(const f16x8*)&((const uint4*)wlds)[(ra << 3) + (kb ^ (ra & 7))];
#pragma unroll
      for (int j = 0; j < 4; ++j) {
        const int rb = (j << 4) + lr;
        const f16x8 bfr = *(const f16x8*)&((const uint4*)vlds)[(rb << 3) + (kb ^ (rb & 7))];
        acc[j] = __builtin_amdgcn_mfma_f32_16x16x32_f16(afr, bfr, acc[j], 0, 0, 0);
      }
    }
  }

  // --- per-block IN partial stats (register-only; no atomics; deterministic)
#pragma unroll
  for (int q = 0; q < 4; ++q) {
    float s = acc[0][q] + acc[1][q] + acc[2][q] + acc[3][q];
    float s2 = fmaf(acc[0][q], acc[0][q],
               fmaf(acc[1][q], acc[1][q],
               fmaf(acc[2][q], acc[2][q], acc[3][q] * acc[3][q])));
#pragma unroll
    for (int m = 1; m < 16; m <<= 1) {
      s += __shfl_xor(s, m);
      s2 += __shfl_xor(s2, m);
    }
    if (lr == 0) {
      const int pll = oo0 + (lg << 2) + q;
      ((float2*)pstats2)[(size_t)t * 64 + pll] = make_float2(s, s2);
    }
  }

  // --- epilogue: transpose through (now dead) LDS -> coalesced fp16 stores
  __syncthreads();  // all MFMA reads of smem done
  float* fsm = (float*)smem;  // [64 o][64 px] f32 = 16 KB
#pragma unroll
  for (int j = 0; j < 4; ++j)
#pragma unroll
    for (int q = 0; q < 4; ++q)
      fsm[(oo0 + (lg << 2) + q) * 64 + (j << 4) + lr] = acc[j][q];
  __syncthreads();
  {
    const float4* fsm4 = (const float4*)fsm;
    unsigned short* prebase = pre16 + (size_t)b * O_ * HW_ + p0;
#pragma unroll
    for (int i = 0; i < 4; ++i) {
      const int f = tid + (i << 8);
      const int o = f >> 4;
      const int px4 = (f & 15) << 2;
      const float4 v = fsm4[f];
      uint2 pk;
      pk.x = pkh(v.x, v.y);
      pk.y = pkh(v.z, v.w);
      *(uint2*)&prebase[(size_t)o * HW_ + px4] = pk;
    }
  }
}

// ---------------- K5: fused stats-finalize + instance norm + ReLU --------------
// Each block re-reduces its plane's 576 partials (L2-resident, fixed order ->
// deterministic, identical across blocks of a plane), then normalizes 1024 px.
__global__ __launch_bounds__(256) void k5_norm(const unsigned short* __restrict__ pre16,
                                               const float* __restrict__ pstats2,
                                               float* __restrict__ out) {
  const int blk = blockIdx.x;        // 1152 blocks; 9 blocks per plane
  const int plane = blk / 9;         // b*O + o
  const int b = plane >> 6, o = plane & 63;
  const int tid = threadIdx.x;

  // --- redundant per-block stats reduction (576 float2 partials)
  const float2* src = (const float2*)pstats2 + (size_t)b * 576 * 64 + o;
  float s = 0.f, s2 = 0.f;
  for (int tt = tid; tt < 576; tt += 256) {
    const float2 v = src[(size_t)tt * 64];
    s += v.x;
    s2 += v.y;
  }
#pragma unroll
  for (int m = 1; m < 64; m <<= 1) {
    s += __shfl_xor(s, m);
    s2 += __shfl_xor(s2, m);
  }
  __shared__ float ls[4], ls2[4], mrs[2];
  const int wid = tid >> 6;
  if ((tid & 63) == 0) { ls[wid] = s; ls2[wid] = s2; }
  __syncthreads();
  if (tid == 0) {
    const float ts = ls[0] + ls[1] + ls[2] + ls[3];
    const float ts2 = ls2[0] + ls2[1] + ls2[2] + ls2[3];
    const float inv = 1.f / (float)HW_;
    const float mu = ts * inv;
    const float var = fmaxf(fmaf(-mu, mu, ts2 * inv), 0.f);
    mrs[0] = mu;
    mrs[1] = rsqrtf(var + EPS_);
  }
  __syncthreads();
  const float mu = mrs[0], rs = mrs[1];

  // --- normalize + ReLU: this block's 1024-px chunk of the plane
  const int chunk = blk - plane * 9;  // 0..8
  const int i4 = (plane * 9 + chunk) * 1024 + tid;  // == blk*1024 + tid
  const uint2 pk0 = ((const uint2*)pre16)[i4];
  const uint2 pk1 = ((const uint2*)pre16)[i4 + 256];
  const uint2 pk2 = ((const uint2*)pre16)[i4 + 512];
  const uint2 pk3 = ((const uint2*)pre16)[i4 + 768];
  const uint2 pks[4] = {pk0, pk1, pk2, pk3};
#pragma unroll
  for (int i = 0; i < 4; ++i) {
    const __half2 h0 = *(const __half2*)&pks[i].x;
    const __half2 h1 = *(const __half2*)&pks[i].y;
    const float2 f0 = __half22float2(h0);
    const float2 f1 = __half22float2(h1);
    float4 v;
    v.x = fmaxf((f0.x - mu) * rs, 0.f);
    v.y = fmaxf((f0.y - mu) * rs, 0.f);
    v.z = fmaxf((f1.x - mu) * rs, 0.f);
    v.w = fmaxf((f1.y - mu) * rs, 0.f);
    ((float4*)out)[i4 + i * 256] = v;
  }
}

extern "C" void kernel_launch(void* const* d_in, const int* in_sizes, int n_in,
                              void* d_out, int out_size, void* d_ws, size_t ws_size,
                              hipStream_t stream) {
  const float* x = (const float*)d_in[0];
  const float* dw_w = (const float*)d_in[1];
  const float* dw_b = (const float*)d_in[2];
  const float* bn_g = (const float*)d_in[3];
  const float* bn_b = (const float*)d_in[4];
  const float* bn_m = (const float*)d_in[5];
  const float* bn_v = (const float*)d_in[6];
  const float* pw_w = (const float*)d_in[7];
  const float* pw_b = (const float*)d_in[8];
  const float* dcn_w = (const float*)d_in[9];
  float* out = (float*)d_out;

  // workspace layout (d_ws; pstats2 moved here: k5 reads it while writing d_out)
  unsigned short* h16 = (unsigned short*)d_ws;               // B*C*HW fp16 = 4.7 MB
  float4* om4 = (float4*)(h16 + (size_t)B_ * C_ * HW_);      // B*9*HW float4 = 10.6 MB
  unsigned short* pre16 = (unsigned short*)(om4 + (size_t)B_ * 9 * HW_);  // 4.7 MB
  unsigned short* wT2 = pre16 + (size_t)B_ * O_ * HW_;       // 72 KB
  float* pstats2 = (float*)(wT2 + (size_t)K_ * O_ * C_);     // 1152*64*2 f = 590 KB
  if (ws_size < (size_t)(4718592 + 10616832 + 4718592 + 73728 + 589824 + 64)) return;
  // xR (gather-layout fp16, 9.4 MB) lives in d_out: dead after k3, before k5 writes.
  unsigned short* xR = (unsigned short*)d_out;

  k_front<<<dim3(HW_ / 256, 131), dim3(256), 0, stream>>>(x, dw_w, dw_b, bn_g, bn_b,
                                                          bn_m, bn_v, dcn_w,
                                                          h16, xR, wT2);
  k2_pw<<<dim3(HW_ / 256, B_), dim3(256), 0, stream>>>(h16, pw_w, pw_b, om4);
  k3_dcn<<<dim3(B_ * HW_ / 64), dim3(256), 0, stream>>>(xR, om4, wT2, pre16, pstats2);
  k5_norm<<<dim3(B_ * O_ * 9), dim3(256), 0, stream>>>(pre16, pstats2, out);
}